// Round 15
// baseline (24.612 us; speedup 1.0000x reference)
//
#include <hip/hip_runtime.h>
#include <math.h>

// DMLoss fused kernel for MI355X (gfx950).
// Round 15: zero-DS scan via DPP rotation. Scans pay 14 VALU + 2 DS per
// candidate; DS is a per-CU pipe (4 SIMDs share it) => ~8us structural tax.
// New: thread owns ONE point; a DPP row's 16 lanes hold 16 segments resident
// in VGPRs; the point + its traveling best (u64 (d_bits<<32)|idx, exact
// first-occurrence ties, proven R12) rotates via row_ror:1. 128 candidates =
// 16 DS reads + zero merges. Phase B and C run in different waves
// concurrently. 2048 blocks x 128 threads -> 32 waves/CU; roles swapped by
// block parity for SIMD balance.

#define BB 1024
#define NN 128
#define MM 128

typedef unsigned long long u64;
typedef unsigned int u32;

__device__ __forceinline__ float sl1(float x) {
    float d = fabsf(x);
    return d < 1.0f ? 0.5f * d * d : d - 0.5f;
}

__device__ __forceinline__ float dpp_ror1_f(float v) {
    return __builtin_bit_cast(float,
        __builtin_amdgcn_mov_dpp(__builtin_bit_cast(int, v), 0x121, 0xf, 0xf, false));
}
__device__ __forceinline__ u32 dpp_ror1_u(u32 v) {
    return (u32)__builtin_amdgcn_mov_dpp((int)v, 0x121, 0xf, 0xf, false);
}

__global__ void __launch_bounds__(128, 8)
dmloss_main(const float* __restrict__ ini, const float* __restrict__ pred,
            const float* __restrict__ gt,  const float* __restrict__ kmask,
            float4* __restrict__ partials)
{
    const int bid  = blockIdx.x;
    const int b    = bid >> 1;
    const int half = bid & 1;            // point range [64*half, 64*half+64)
    const int tid  = threadIdx.x;
    const int wid  = tid >> 6;           // 0..1
    const int lane = tid & 63;
    const int lr   = lane & 15;          // lane within DPP row
    const int role = wid ^ half;         // 0: phase B wave, 1: phase C wave
    const int P    = (half << 6) + lane; // owned point 0..127

    __shared__ float2 s_gt[MM];
    __shared__ float4 s_segA[MM];        // (ax, ay, Xn, Yn)
    __shared__ float2 s_segB[MM];        // (ex/10, ey/10)
    __shared__ float2 s_pr[NN];
    __shared__ float2 s_ii[NN];
    __shared__ float  s_step[16];
    __shared__ float  s_sum[3][2];

    const float2* gt2 = (const float2*)(gt   + (size_t)b * MM * 2);
    const float2* in2 = (const float2*)(ini  + (size_t)b * NN * 2);
    const float2* pr2 = (const float2*)(pred + (size_t)b * NN * 2);

    // ---- staging: 128 threads build all tables ----
    {
        int m = tid;
        float2 gm = gt2[m];
        float2 a  = gt2[(m + 127) & 127];
        s_gt[m] = gm;
        float ex = gm.x - a.x, ey = gm.y - a.y;
        float A  = ex * ex + ey * ey;
        float inv = A > 0.f ? 10.f / A : 0.f;   // degenerate seg -> vertex 0
        s_segA[m] = make_float4(a.x, a.y, -ex * inv, -ey * inv);
        s_segB[m] = make_float2(ex * 0.1f, ey * 0.1f);
        s_ii[m] = in2[m];
        s_pr[m] = pr2[m];
        if (tid < 16) s_step[tid] = (float)tid / 10.0f;
    }
    // Own-point data (coalesced; used per role)
    float2 myP  = in2[P];
    float2 myPr = pr2[P];
    float2 myG  = gt2[P];
    float  myKm = kmask[b * MM + P];
    __syncthreads();

    float sumA = 0.f, sumB = 0.f, sumC = 0.f;

    if (role == 0) {
        // ---- Phase B: own pred point rotates; lanes hold segments ----
        // Segment m: a=gt[m-1], e=gt[m]-a, q=a-p; jv=qx*Xn+qy*Yn; jr=rint(med3);
        // d=|q+(e/10)*jr|^2; key = (d_bits<<32) | (10m+jr).
        float px = myP.x, py = myP.y;
        u64 best = 0x7F800000FFFFFFFFull;    // d=+inf
        #pragma unroll 2
        for (int g = 0; g < 8; ++g) {
            float4 SA = s_segA[16 * g + lr];     // per-lane resident constants
            float2 SB = s_segB[16 * g + lr];
            float base = (float)(10 * (16 * g + lr));
            #pragma unroll
            for (int t = 0; t < 16; ++t) {
                float qx = SA.x - px, qy = SA.y - py;
                float jv = fmaf(qy, SA.w, qx * SA.z);
                float jr = rintf(__builtin_amdgcn_fmed3f(jv, 0.f, 9.f));
                float dx = fmaf(jr, SB.x, qx);
                float dy = fmaf(jr, SB.y, qy);
                float d  = fmaf(dy, dy, dx * dx);
                u64 c = ((u64)__builtin_bit_cast(u32, d) << 32)
                        | (u32)(base + jr);
                best = c < best ? c : best;      // exact lexicographic argmin
                // rotate point + traveling best to next lane in the row
                px = dpp_ror1_f(px);
                py = dpp_ror1_f(py);
                u32 bl = dpp_ror1_u((u32)best);
                u32 bh = dpp_ror1_u((u32)(best >> 32));
                best = ((u64)bh << 32) | bl;
            }
        }
        // point + best are home; exact epilogue A
        u32 idx = (u32)best;
        int m = (int)idx / 10;
        int j = (int)idx - 10 * m;
        float s  = s_step[j];
        float tt = 1.0f - s;
        float2 gm = s_gt[m];
        float2 gp = s_gt[(m + 127) & 127];
        float gx = gm.x * s + gp.x * tt;   // exact reference interp formula
        float gy = gm.y * s + gp.y * tt;
        sumA = sl1(myPr.x - gx) + sl1(myPr.y - gy);
    } else {
        // ---- Phase C: own gt point rotates; lanes hold ini points ----
        float gx = myG.x, gy = myG.y;
        u64 best = 0x7F800000FFFFFFFFull;
        #pragma unroll 2
        for (int g = 0; g < 8; ++g) {
            float2 I = s_ii[16 * g + lr];
            const u32 lo = (u32)(16 * g + lr);
            #pragma unroll
            for (int t = 0; t < 16; ++t) {
                float dx = I.x - gx, dy = I.y - gy;
                float d  = fmaf(dy, dy, dx * dx);
                u64 c = ((u64)__builtin_bit_cast(u32, d) << 32) | lo;
                best = c < best ? c : best;
                gx = dpp_ror1_f(gx);
                gy = dpp_ror1_f(gy);
                u32 bl = dpp_ror1_u((u32)best);
                u32 bh = dpp_ror1_u((u32)(best >> 32));
                best = ((u64)bh << 32) | bl;
            }
        }
        u32 k = (u32)best;
        float2 pk = s_pr[k];
        sumB = myKm * (sl1(pk.x - myG.x) + sl1(pk.y - myG.y));
        sumC = myKm;
    }

    // ---- block reduction (2 waves) ----
    #pragma unroll
    for (int off = 32; off > 0; off >>= 1) {
        sumA += __shfl_down(sumA, off);
        sumB += __shfl_down(sumB, off);
        sumC += __shfl_down(sumC, off);
    }
    if (lane == 0) {
        s_sum[0][wid] = sumA; s_sum[1][wid] = sumB; s_sum[2][wid] = sumC;
    }
    __syncthreads();
    if (tid == 0) {
        partials[bid] = make_float4(s_sum[0][0] + s_sum[0][1],
                                    s_sum[1][0] + s_sum[1][1],
                                    s_sum[2][0] + s_sum[2][1], 0.0f);
    }
}

__global__ void __launch_bounds__(256)
dmloss_final(const float4* __restrict__ partials, float* __restrict__ out)
{
    const int tid = threadIdx.x;
    float A = 0.0f, Bs = 0.0f, C = 0.0f;
    #pragma unroll
    for (int i = tid; i < 2 * BB; i += 256) {
        float4 p = partials[i];
        A += p.x; Bs += p.y; C += p.z;
    }
    #pragma unroll
    for (int off = 32; off > 0; off >>= 1) {
        A  += __shfl_down(A, off);
        Bs += __shfl_down(Bs, off);
        C  += __shfl_down(C, off);
    }
    __shared__ float sA[4], sB[4], sC[4];
    const int wave = tid >> 6, lane = tid & 63;
    if (lane == 0) { sA[wave] = A; sB[wave] = Bs; sC[wave] = C; }
    __syncthreads();
    if (tid == 0) {
        float a  = sA[0] + sA[1] + sA[2] + sA[3];
        float bs = sB[0] + sB[1] + sB[2] + sB[3];
        float c  = sC[0] + sC[1] + sC[2] + sC[3];
        float loss_pred2gt = a / ((float)BB * (float)NN * 2.0f);
        float loss_set2set = bs / (2.0f * c + 1.0f) + loss_pred2gt;
        out[0] = 0.5f * loss_set2set;
    }
}

extern "C" void kernel_launch(void* const* d_in, const int* in_sizes, int n_in,
                              void* d_out, int out_size, void* d_ws, size_t ws_size,
                              hipStream_t stream)
{
    const float* ini   = (const float*)d_in[0];
    const float* pred  = (const float*)d_in[1];
    const float* gt    = (const float*)d_in[2];
    const float* kmask = (const float*)d_in[3];
    float4* partials = (float4*)d_ws;   // 2048 * 16 B = 32 KiB

    dmloss_main<<<dim3(2 * BB), dim3(128), 0, stream>>>(ini, pred, gt, kmask, partials);
    dmloss_final<<<dim3(1), dim3(256), 0, stream>>>(partials, (float*)d_out);
}

// Round 16
// 17.891 us; speedup vs baseline: 1.3757x; 1.3757x over previous
//
#include <hip/hip_runtime.h>
#include <math.h>

// DMLoss fused kernel for MI355X (gfx950).
// Round 16: rolling-D Phase B (algebraic fusion). q.e = (Dg - Da - |e|^2)/2
// => jv = (Da - Dg)*(5/|e|^2) + 5 and d = Da + E*jr*(jr - 2*jv), with
// Da = dist^2(p, gt[m-1]) rolling into Dg = dist^2(p, gt[m]) across the
// m-loop. Segment-start coords vanish: ONE fused float4 (gx, gy, 5/A, A/100)
// = 16 B (12 cyc) per candidate vs b128+b64 = 24 B (18 cyc) in R14. VALU
// ~same. Single-variable change from R14 (best, 18.1us): 256-thr blocks,
// merges, epilogues, final kernel identical.

#define BB 1024
#define NN 128
#define MM 128

__device__ __forceinline__ float sl1(float x) {
    float d = fabsf(x);
    return d < 1.0f ? 0.5f * d * d : d - 0.5f;
}

__global__ void __launch_bounds__(256, 8)
dmloss_main(const float* __restrict__ ini, const float* __restrict__ pred,
            const float* __restrict__ gt,  const float* __restrict__ kmask,
            float4* __restrict__ partials)
{
    const int b    = blockIdx.x >> 1;
    const int half = blockIdx.x & 1;      // owns points [64*half, 64*half+64)
    const int tid  = threadIdx.x;
    const int g    = tid & 63;            // owned point: P = 64*half + g
    const int h    = tid >> 6;            // 0..3: scan slice (32 segs / 32 ini)
    const int P    = (half << 6) + g;

    __shared__ __align__(16) float2 s_gt[MM];
    __shared__ float2 s_pr[NN];
    __shared__ float2 s_ii[NN];
    __shared__ float4 s_seg[MM];                 // (gx, gy, 5/|e|^2, |e|^2/100)
    __shared__ float  s_step[16];                // exact j/10
    __shared__ float  s_rv[4 * 64];
    __shared__ float  s_rf[4 * 64];
    __shared__ float  s_sum[3][4];

    const float2* gt2 = (const float2*)(gt   + (size_t)b * MM * 2);
    const float2* in2 = (const float2*)(ini  + (size_t)b * NN * 2);
    const float2* pr2 = (const float2*)(pred + (size_t)b * NN * 2);

    // ---- staging (one barrier): 256 threads cover 128 segs + 128 pr/ii ----
    if (tid < 128) {
        int m = tid;
        float2 gm = gt2[m];
        float2 a  = gt2[(m + 127) & 127];
        s_gt[m] = gm;
        float ex = gm.x - a.x, ey = gm.y - a.y;
        float A  = ex * ex + ey * ey;
        float inv5 = A > 0.f ? 5.f / A : 0.f;   // degenerate: jv=5, E=0 -> d=Da
        s_seg[m] = make_float4(gm.x, gm.y, inv5, A * 0.01f);
        if (tid < 16) s_step[tid] = (float)tid / 10.0f;
    } else {
        int k = tid - 128;
        s_pr[k] = pr2[k];
        s_ii[k] = in2[k];
    }
    // Own point data (register-resident; coalesced within each wave).
    float2 myP  = in2[P];                  // ini_pred point (scanned against segs)
    float2 myG  = gt2[P];                  // gt point (Phase C owner)
    const float px = myP.x, py = myP.y;
    __syncthreads();

    float sumA = 0.f, sumB = 0.f, sumC = 0.f;

    // ---- Phase B: owned pred point vs segment slice [32h, 32h+32) ----
    // Rolling D: Da = dist^2(p, gt[m-1]); Dg = dist^2(p, gt[m]).
    // jv = (Da-Dg)*inv5 + 5; jr = rint(med3(jv,0,9));
    // d = Da + (E*jr)*(jr - 2*jv); fi = 10*m + jr.
    float b0 = INFINITY, f0 = 1e30f;
    {
        const int m0 = 32 * h;
        // init Da = dist^2(p, gt[m0-1])
        float2 a0 = s_gt[(m0 + 127) & 127];
        float dax = a0.x - px, day = a0.y - py;
        float Da = fmaf(day, day, dax * dax);
        float fm = (float)(320 * h);
        #pragma unroll 4
        for (int j = 0; j < 32; ++j) {
            float4 S = s_seg[m0 + j];                 // wave-uniform broadcast
            float dgx = S.x - px, dgy = S.y - py;
            float Dg  = fmaf(dgy, dgy, dgx * dgx);
            float jv  = fmaf(Da - Dg, S.z, 5.0f);
            float jr  = rintf(__builtin_amdgcn_fmed3f(jv, 0.f, 9.f));
            float t   = fmaf(jv, -2.f, jr);           // jr - 2*jv
            float d   = fmaf(S.w * jr, t, Da);
            float fi  = fm + jr;
            if (d < b0) { b0 = d; f0 = fi; }          // ascending -> first occ.
            Da = Dg;
            fm += 10.f;
        }
    }
    s_rv[h * 64 + g] = b0;
    s_rf[h * 64 + g] = f0;
    __syncthreads();

    // merge 4 slices (64 active threads) + exact epilogue A
    if (tid < 64) {
        float best = s_rv[tid], bf = s_rf[tid];
        #pragma unroll
        for (int q = 1; q < 4; ++q) {
            float ov = s_rv[q * 64 + tid];
            float of = s_rf[q * 64 + tid];
            if (ov < best || (ov == best && of < bf)) { best = ov; bf = of; }
        }
        int bidx = (int)bf;
        int m = bidx / 10;
        int j = bidx - m * 10;
        float s  = s_step[j];
        float tt = 1.0f - s;
        float2 gm = s_gt[m];
        float2 gp = s_gt[(m + 127) & 127];
        float gx = gm.x * s + gp.x * tt;   // exact reference interp formula
        float gy = gm.y * s + gp.y * tt;
        float2 pr = s_pr[(half << 6) + tid];
        sumA = sl1(pr.x - gx) + sl1(pr.y - gy);
    }
    __syncthreads();   // protect s_rv/s_rf reuse

    // ---- Phase C: owned gt point vs ini slice [32h, 32h+32) ----
    {
        const float gx = myG.x, gy = myG.y;
        float b1 = INFINITY, f1 = 1e30f;
        float fk = (float)(32 * h);
        const int k0 = 32 * h;
        #pragma unroll 4
        for (int j = 0; j < 32; ++j) {
            float2 I = s_ii[k0 + j];                  // wave-uniform broadcast
            float dx = I.x - gx, dy = I.y - gy;
            float d  = fmaf(dy, dy, dx * dx);
            if (d < b1) { b1 = d; f1 = fk; }
            fk += 1.f;
        }
        s_rv[h * 64 + g] = b1;
        s_rf[h * 64 + g] = f1;
    }
    __syncthreads();

    if (tid < 64) {
        float best = s_rv[tid], bf = s_rf[tid];
        #pragma unroll
        for (int q = 1; q < 4; ++q) {
            float ov = s_rv[q * 64 + tid];
            float of = s_rf[q * 64 + tid];
            if (ov < best || (ov == best && of < bf)) { best = ov; bf = of; }
        }
        int k = (int)bf;
        float2 pk2 = s_pr[k];
        float2 g0  = s_gt[(half << 6) + tid];
        float  km  = kmask[b * MM + (half << 6) + tid];
        sumB = km * (sl1(pk2.x - g0.x) + sl1(pk2.y - g0.y));
        sumC = km;
    }

    // ---- Block reduction ----
    #pragma unroll
    for (int off = 32; off > 0; off >>= 1) {
        sumA += __shfl_down(sumA, off);
        sumB += __shfl_down(sumB, off);
        sumC += __shfl_down(sumC, off);
    }
    const int wave = tid >> 6;
    if ((tid & 63) == 0) {
        s_sum[0][wave] = sumA; s_sum[1][wave] = sumB; s_sum[2][wave] = sumC;
    }
    __syncthreads();
    if (tid == 0) {
        float A = 0.f, Bs = 0.f, C = 0.f;
        #pragma unroll
        for (int w = 0; w < 4; ++w) {
            A += s_sum[0][w]; Bs += s_sum[1][w]; C += s_sum[2][w];
        }
        partials[blockIdx.x] = make_float4(A, Bs, C, 0.0f);
    }
}

__global__ void __launch_bounds__(256)
dmloss_final(const float4* __restrict__ partials, float* __restrict__ out)
{
    const int tid = threadIdx.x;
    float A = 0.0f, Bs = 0.0f, C = 0.0f;
    #pragma unroll
    for (int i = tid; i < 2 * BB; i += 256) {
        float4 p = partials[i];
        A += p.x; Bs += p.y; C += p.z;
    }
    #pragma unroll
    for (int off = 32; off > 0; off >>= 1) {
        A  += __shfl_down(A, off);
        Bs += __shfl_down(Bs, off);
        C  += __shfl_down(C, off);
    }
    __shared__ float sA[4], sB[4], sC[4];
    const int wave = tid >> 6, lane = tid & 63;
    if (lane == 0) { sA[wave] = A; sB[wave] = Bs; sC[wave] = C; }
    __syncthreads();
    if (tid == 0) {
        float a  = sA[0] + sA[1] + sA[2] + sA[3];
        float bs = sB[0] + sB[1] + sB[2] + sB[3];
        float c  = sC[0] + sC[1] + sC[2] + sC[3];
        float loss_pred2gt = a / ((float)BB * (float)NN * 2.0f);
        float loss_set2set = bs / (2.0f * c + 1.0f) + loss_pred2gt;
        out[0] = 0.5f * loss_set2set;
    }
}

extern "C" void kernel_launch(void* const* d_in, const int* in_sizes, int n_in,
                              void* d_out, int out_size, void* d_ws, size_t ws_size,
                              hipStream_t stream)
{
    const float* ini   = (const float*)d_in[0];
    const float* pred  = (const float*)d_in[1];
    const float* gt    = (const float*)d_in[2];
    const float* kmask = (const float*)d_in[3];
    float4* partials = (float4*)d_ws;   // 2048 * 16 B = 32 KiB

    dmloss_main<<<dim3(2 * BB), dim3(256), 0, stream>>>(ini, pred, gt, kmask, partials);
    dmloss_final<<<dim3(1), dim3(256), 0, stream>>>(partials, (float*)d_out);
}